// Round 3
// baseline (32.582 us; speedup 1.0000x reference)
//
#include <hip/hip_runtime.h>
#include <math.h>

// out[b,n,e] = BOUND * tanh( slope/BOUND * w_scale * (sum_d x[d]*w[d][e]) / max(sqrt(sum_d w[d][e]^2), 1e-12) )
// B*N = 8192 pairs, D = E = 64. One wave per (b,n) pair, 4 waves/block.
// Lane (dq,c) = (lane>>4, lane&15): cols 4c..4c+3, rows d = 16*dq + k, k=0..15.
// Key change vs r2: x[d] needed by lane for batch t is exactly float4 xp4[4*dq+t]
// -> zero cross-lane shuffles (no ds_bpermute / lgkmcnt) in the inner loop.
// Per w-load instruction the wave covers 4 contiguous 256 B row segments.

#define BOUND_F 1.8477590650225735f

__global__ __launch_bounds__(256, 8) void node_matvec_kernel(
    const float* __restrict__ x,        // [BN, 64]
    const float* __restrict__ w,        // [BN, 64, 64]  (d-major, e contiguous)
    const float* __restrict__ w_scale_p,
    const float* __restrict__ slope_p,
    float* __restrict__ out,            // [BN, 64]
    int bn_total)
{
    const int wave = threadIdx.x >> 6;
    const int lane = threadIdx.x & 63;
    const int bn   = blockIdx.x * 4 + wave;   // one (b,n) per wave
    if (bn >= bn_total) return;

    const int c  = lane & 15;   // column group: cols 4c..4c+3
    const int dq = lane >> 4;   // row quarter: d = 16*dq + k

    const float4* __restrict__ wp = (const float4*)(w + (size_t)bn * 4096);
    const float4* __restrict__ xp = (const float4*)(x + (size_t)bn * 64);

    float4 dot = make_float4(0.f, 0.f, 0.f, 0.f);
    float4 sq  = make_float4(0.f, 0.f, 0.f, 0.f);

    float4 wbuf[2][4];
    float4 xbuf[2];

    // prologue: batch 0 (k = 0..3)
    xbuf[0] = xp[4 * dq + 0];
#pragma unroll
    for (int j = 0; j < 4; ++j)
        wbuf[0][j] = wp[(16 * dq + j) * 16 + c];

#pragma unroll
    for (int t = 0; t < 4; ++t) {               // 4 batches of 4 k-steps
        const int cur = t & 1;
        const int nxt = cur ^ 1;
        if (t < 3) {
            xbuf[nxt] = xp[4 * dq + (t + 1)];
#pragma unroll
            for (int j = 0; j < 4; ++j)
                wbuf[nxt][j] = wp[(16 * dq + 4 * (t + 1) + j) * 16 + c];
        }
        const float4 xv = xbuf[cur];
#pragma unroll
        for (int j = 0; j < 4; ++j) {
            const float4 wv = wbuf[cur][j];
            const float  xj = (j == 0) ? xv.x : (j == 1) ? xv.y : (j == 2) ? xv.z : xv.w;
            dot.x = fmaf(xj, wv.x, dot.x);
            dot.y = fmaf(xj, wv.y, dot.y);
            dot.z = fmaf(xj, wv.z, dot.z);
            dot.w = fmaf(xj, wv.w, dot.w);
            sq.x  = fmaf(wv.x, wv.x, sq.x);
            sq.y  = fmaf(wv.y, wv.y, sq.y);
            sq.z  = fmaf(wv.z, wv.z, sq.z);
            sq.w  = fmaf(wv.w, wv.w, sq.w);
        }
    }

    // reduce the 4 row-quarter partials: lanes {c, c+16, c+32, c+48}
#pragma unroll
    for (int m = 16; m <= 32; m <<= 1) {
        dot.x += __shfl_xor(dot.x, m, 64);
        dot.y += __shfl_xor(dot.y, m, 64);
        dot.z += __shfl_xor(dot.z, m, 64);
        dot.w += __shfl_xor(dot.w, m, 64);
        sq.x  += __shfl_xor(sq.x,  m, 64);
        sq.y  += __shfl_xor(sq.y,  m, 64);
        sq.z  += __shfl_xor(sq.z,  m, 64);
        sq.w  += __shfl_xor(sq.w,  m, 64);
    }

    if (dq == 0) {
        const float ws = w_scale_p[0];
        const float sl = slope_p[0];
        const float s  = sl * (1.0f / BOUND_F);
        float4 o;
        o.x = BOUND_F * tanhf(s * (ws * dot.x / fmaxf(sqrtf(sq.x), 1e-12f)));
        o.y = BOUND_F * tanhf(s * (ws * dot.y / fmaxf(sqrtf(sq.y), 1e-12f)));
        o.z = BOUND_F * tanhf(s * (ws * dot.z / fmaxf(sqrtf(sq.z), 1e-12f)));
        o.w = BOUND_F * tanhf(s * (ws * dot.w / fmaxf(sqrtf(sq.w), 1e-12f)));
        ((float4*)(out + (size_t)bn * 64))[c] = o;
    }
}

extern "C" void kernel_launch(void* const* d_in, const int* in_sizes, int n_in,
                              void* d_out, int out_size, void* d_ws, size_t ws_size,
                              hipStream_t stream) {
    const float* x  = (const float*)d_in[0];
    const float* w  = (const float*)d_in[1];
    const float* ws = (const float*)d_in[2];
    const float* sl = (const float*)d_in[3];
    // d_in[4] = step_counter (unused by the reference computation)
    float* out = (float*)d_out;

    const int bn_total = in_sizes[0] / 64;         // B*N = 8192
    const int grid = (bn_total + 3) / 4;           // 4 waves (pairs) per block

    hipLaunchKernelGGL(node_matvec_kernel, dim3(grid), dim3(256), 0, stream,
                       x, w, ws, sl, out, bn_total);
}

// Round 4
// 25.694 us; speedup vs baseline: 1.2681x; 1.2681x over previous
//
#include <hip/hip_runtime.h>
#include <math.h>

// out[b,n,e] = BOUND * tanh( slope/BOUND * w_scale * (sum_d x[d]*w[d][e]) / max(sqrt(sum_d w[d][e]^2), 1e-12) )
// B*N = 8192 pairs, D = E = 64. One wave (64 lanes) per (b,n) pair.
// R1 access pattern (proven best): lane (dq,c) = (lane>>4, lane&15), rows d = 4k+dq,
// per-k the wave's 64 float4 loads form ONE contiguous 1 KB segment.
// R4 change: nontemporal (nt) loads on the zero-reuse weight stream + nt store on out,
// bypassing cache allocation on the 134 MB stream.

#define BOUND_F 1.8477590650225735f

typedef float v4f __attribute__((ext_vector_type(4)));

__global__ __launch_bounds__(256, 4) void node_matvec_kernel(
    const float* __restrict__ x,        // [BN, 64]
    const float* __restrict__ w,        // [BN, 64, 64]  (d-major, e contiguous)
    const float* __restrict__ w_scale_p,
    const float* __restrict__ slope_p,
    float* __restrict__ out,            // [BN, 64]
    int bn_total)
{
    const int wave = threadIdx.x >> 6;
    const int lane = threadIdx.x & 63;
    const int bn   = blockIdx.x * 4 + wave;   // one (b,n) per wave
    if (bn >= bn_total) return;

    const int c  = lane & 15;   // column group: cols 4c..4c+3
    const int dq = lane >> 4;   // row phase 0..3

    const float xreg = x[bn * 64 + lane];

    const v4f* __restrict__ wp = (const v4f*)(w + (size_t)bn * 4096);

    v4f dot = {0.f, 0.f, 0.f, 0.f};
    v4f sq  = {0.f, 0.f, 0.f, 0.f};

#pragma unroll
    for (int k = 0; k < 16; ++k) {
        const int d = 4 * k + dq;
        const v4f  wv = __builtin_nontemporal_load(wp + d * 16 + c);  // contiguous 1KB/wave
        const float xv = __shfl(xreg, d, 64);  // broadcast x[d]
        dot.x = fmaf(xv, wv.x, dot.x);
        dot.y = fmaf(xv, wv.y, dot.y);
        dot.z = fmaf(xv, wv.z, dot.z);
        dot.w = fmaf(xv, wv.w, dot.w);
        sq.x  = fmaf(wv.x, wv.x, sq.x);
        sq.y  = fmaf(wv.y, wv.y, sq.y);
        sq.z  = fmaf(wv.z, wv.z, sq.z);
        sq.w  = fmaf(wv.w, wv.w, sq.w);
    }

    // reduce the 4 row-phase partials: lanes {c, c+16, c+32, c+48}
#pragma unroll
    for (int m = 16; m <= 32; m <<= 1) {
        dot.x += __shfl_xor(dot.x, m, 64);
        dot.y += __shfl_xor(dot.y, m, 64);
        dot.z += __shfl_xor(dot.z, m, 64);
        dot.w += __shfl_xor(dot.w, m, 64);
        sq.x  += __shfl_xor(sq.x,  m, 64);
        sq.y  += __shfl_xor(sq.y,  m, 64);
        sq.z  += __shfl_xor(sq.z,  m, 64);
        sq.w  += __shfl_xor(sq.w,  m, 64);
    }

    if (dq == 0) {
        const float ws = w_scale_p[0];
        const float sl = slope_p[0];
        const float s  = sl * (1.0f / BOUND_F);
        v4f o;
        o.x = BOUND_F * tanhf(s * (ws * dot.x / fmaxf(sqrtf(sq.x), 1e-12f)));
        o.y = BOUND_F * tanhf(s * (ws * dot.y / fmaxf(sqrtf(sq.y), 1e-12f)));
        o.z = BOUND_F * tanhf(s * (ws * dot.z / fmaxf(sqrtf(sq.z), 1e-12f)));
        o.w = BOUND_F * tanhf(s * (ws * dot.w / fmaxf(sqrtf(sq.w), 1e-12f)));
        __builtin_nontemporal_store(o, (v4f*)(out + (size_t)bn * 64) + c);
    }
}

extern "C" void kernel_launch(void* const* d_in, const int* in_sizes, int n_in,
                              void* d_out, int out_size, void* d_ws, size_t ws_size,
                              hipStream_t stream) {
    const float* x  = (const float*)d_in[0];
    const float* w  = (const float*)d_in[1];
    const float* ws = (const float*)d_in[2];
    const float* sl = (const float*)d_in[3];
    // d_in[4] = step_counter (unused by the reference computation)
    float* out = (float*)d_out;

    const int bn_total = in_sizes[0] / 64;         // B*N = 8192
    const int grid = (bn_total + 3) / 4;           // 4 waves (pairs) per block

    hipLaunchKernelGGL(node_matvec_kernel, dim3(grid), dim3(256), 0, stream,
                       x, w, ws, sl, out, bn_total);
}